// Round 1
// baseline (391.492 us; speedup 1.0000x reference)
//
#include <hip/hip_runtime.h>

#define BN_EPS 1e-5f

// ---------------- degree / CSR construction ----------------

__global__ void count_deg_kernel(const int* __restrict__ col, int* __restrict__ cnt, int E) {
    int e = blockIdx.x * blockDim.x + threadIdx.x;
    if (e < E) atomicAdd(&cnt[col[e]], 1);
}

__global__ void dis_kernel(const int* __restrict__ cnt, float* __restrict__ dis, int N) {
    int i = blockIdx.x * blockDim.x + threadIdx.x;
    if (i < N) dis[i] = rsqrtf((float)(cnt[i] + 1));   // +1 self loop; always > 0
}

// single-block exclusive scan over N counts -> rowptr[0..N], cursor copy
__global__ __launch_bounds__(1024) void scan_kernel(const int* __restrict__ cnt,
                                                    int* __restrict__ rowptr,
                                                    int* __restrict__ cursor, int N) {
    __shared__ int sums[1024];
    int t = threadIdx.x;
    int per = (N + 1023) / 1024;
    int start = t * per;
    int local = 0;
    for (int i = 0; i < per; i++) {
        int idx = start + i;
        if (idx < N) local += cnt[idx];
    }
    sums[t] = local;
    __syncthreads();
    for (int off = 1; off < 1024; off <<= 1) {
        int v = (t >= off) ? sums[t - off] : 0;
        __syncthreads();
        sums[t] += v;
        __syncthreads();
    }
    int run = (t == 0) ? 0 : sums[t - 1];
    for (int i = 0; i < per; i++) {
        int idx = start + i;
        if (idx < N) {
            rowptr[idx] = run;
            cursor[idx] = run;
            run += cnt[idx];
        }
    }
    if (t == 0) rowptr[N] = sums[1023];
}

__global__ void scatter_kernel(const int* __restrict__ row, const int* __restrict__ col,
                               int* __restrict__ cursor, int* __restrict__ adj, int E) {
    int e = blockIdx.x * blockDim.x + threadIdx.x;
    if (e < E) {
        int pos = atomicAdd(&cursor[col[e]], 1);
        adj[pos] = row[e];
    }
}

// ---------------- GEMM: C[M,N] = A'[M,K] @ B[N,K]^T ----------------
// A' = A, or BN+ReLU(A) per-column (channel=k) when APPLY_BN.
// 64x64 tile, BK=16, 256 threads, 4x4 per thread.

template <bool APPLY_BN>
__global__ __launch_bounds__(256) void gemm_tn_kernel(
    const float* __restrict__ A,     // [M,K] row-major
    const float* __restrict__ B,     // [N,K] row-major
    const float* __restrict__ scale, // [K] (used if APPLY_BN)
    const float* __restrict__ shift, // [K]
    float* __restrict__ C,           // [M,N] row-major
    int M, int N, int K) {
    __shared__ float As[16][68];
    __shared__ float Bs[16][68];
    int tid = threadIdx.x;
    int m0 = blockIdx.y * 64;
    int n0 = blockIdx.x * 64;
    int lm = tid >> 2;         // 0..63
    int lk = (tid & 3) * 4;    // 0,4,8,12
    int ty = tid >> 4;         // 0..15
    int tx = tid & 15;         // 0..15

    float acc[4][4] = {};

    for (int k0 = 0; k0 < K; k0 += 16) {
        int am = m0 + lm;
        float4 av;
        if (am < M) {
            av = *(const float4*)(A + (size_t)am * K + k0 + lk);
        } else {
            av = make_float4(0.f, 0.f, 0.f, 0.f);
        }
        if (APPLY_BN) {
            av.x = fmaxf(fmaf(av.x, scale[k0 + lk + 0], shift[k0 + lk + 0]), 0.f);
            av.y = fmaxf(fmaf(av.y, scale[k0 + lk + 1], shift[k0 + lk + 1]), 0.f);
            av.z = fmaxf(fmaf(av.z, scale[k0 + lk + 2], shift[k0 + lk + 2]), 0.f);
            av.w = fmaxf(fmaf(av.w, scale[k0 + lk + 3], shift[k0 + lk + 3]), 0.f);
        }
        As[lk + 0][lm] = av.x;
        As[lk + 1][lm] = av.y;
        As[lk + 2][lm] = av.z;
        As[lk + 3][lm] = av.w;

        float4 bv = *(const float4*)(B + (size_t)(n0 + lm) * K + k0 + lk); // N % 64 == 0
        Bs[lk + 0][lm] = bv.x;
        Bs[lk + 1][lm] = bv.y;
        Bs[lk + 2][lm] = bv.z;
        Bs[lk + 3][lm] = bv.w;

        __syncthreads();
#pragma unroll
        for (int kk = 0; kk < 16; kk++) {
            float a[4], b[4];
#pragma unroll
            for (int i = 0; i < 4; i++) a[i] = As[kk][ty * 4 + i];
#pragma unroll
            for (int j = 0; j < 4; j++) b[j] = Bs[kk][tx * 4 + j];
#pragma unroll
            for (int i = 0; i < 4; i++)
#pragma unroll
                for (int j = 0; j < 4; j++) acc[i][j] = fmaf(a[i], b[j], acc[i][j]);
        }
        __syncthreads();
    }

#pragma unroll
    for (int i = 0; i < 4; i++) {
        int m = m0 + ty * 4 + i;
        if (m < M) {
            float* cp = C + (size_t)m * N + n0 + tx * 4;
#pragma unroll
            for (int j = 0; j < 4; j++) cp[j] = acc[i][j];
        }
    }
}

// ---------------- gather (CSR segment-sum with sym norm) ----------------
// h[v][c] = xl[v][c]*dis[v]^2 + sum_{r in adj(v)} xl[r][c]*dis[r]*dis[v]

template <int CPT> // channels per thread; IC = CPT*256
__global__ __launch_bounds__(256) void gather_kernel(
    const float* __restrict__ xl, const int* __restrict__ rowptr,
    const int* __restrict__ adj, const float* __restrict__ dis,
    float* __restrict__ h, int IC) {
    int v = blockIdx.x;
    float dv = dis[v];
    int c[CPT];
    float acc[CPT];
#pragma unroll
    for (int i = 0; i < CPT; i++) {
        c[i] = threadIdx.x + 256 * i;
        acc[i] = xl[(size_t)v * IC + c[i]] * dv * dv;
    }
    int e0 = rowptr[v], e1 = rowptr[v + 1];
    for (int e = e0; e < e1; e++) {
        int r = adj[e];
        float w = dis[r] * dv;
        const float* xr = xl + (size_t)r * IC;
#pragma unroll
        for (int i = 0; i < CPT; i++) acc[i] = fmaf(xr[c[i]], w, acc[i]);
    }
    float* hv = h + (size_t)v * IC;
#pragma unroll
    for (int i = 0; i < CPT; i++) hv[c[i]] = acc[i];
}

// ---------------- batchnorm stats + finalize ----------------

__global__ __launch_bounds__(256) void bn_stats_kernel(
    const float* __restrict__ h, float* __restrict__ sum, float* __restrict__ sumsq,
    int N, int IC, int rows_per_chunk) {
    int r0 = blockIdx.x * rows_per_chunk;
    int r1 = min(r0 + rows_per_chunk, N);
    for (int cc = threadIdx.x; cc < IC; cc += 256) {
        float s = 0.f, ss = 0.f;
        for (int r = r0; r < r1; r++) {
            float v = h[(size_t)r * IC + cc];
            s += v;
            ss += v * v;
        }
        atomicAdd(&sum[cc], s);
        atomicAdd(&sumsq[cc], ss);
    }
}

__global__ void bn_finalize_kernel(const float* __restrict__ sum, const float* __restrict__ sumsq,
                                   const float* __restrict__ gamma, const float* __restrict__ beta,
                                   float* __restrict__ scale, float* __restrict__ shift,
                                   int N, int IC) {
    int cc = blockIdx.x * blockDim.x + threadIdx.x;
    if (cc < IC) {
        float invN = 1.0f / (float)N;
        float mean = sum[cc] * invN;
        float var = sumsq[cc] * invN - mean * mean;
        float sc = gamma[cc] * rsqrtf(var + BN_EPS);
        scale[cc] = sc;
        shift[cc] = beta[cc] - mean * sc;
    }
}

// ---------------- final: out = relu(bn2(h2) + x) ----------------

__global__ void final_kernel(const float* __restrict__ h2, const float* __restrict__ x,
                             const float* __restrict__ scale, const float* __restrict__ shift,
                             float* __restrict__ out, int total4, int C4) {
    int idx = blockIdx.x * blockDim.x + threadIdx.x;
    if (idx >= total4) return;
    int c4 = (idx % C4) * 4;
    float4 h = ((const float4*)h2)[idx];
    float4 xv = ((const float4*)x)[idx];
    float4 o;
    o.x = fmaxf(fmaf(h.x, scale[c4 + 0], shift[c4 + 0]) + xv.x, 0.f);
    o.y = fmaxf(fmaf(h.y, scale[c4 + 1], shift[c4 + 1]) + xv.y, 0.f);
    o.z = fmaxf(fmaf(h.z, scale[c4 + 2], shift[c4 + 2]) + xv.z, 0.f);
    o.w = fmaxf(fmaf(h.w, scale[c4 + 3], shift[c4 + 3]) + xv.w, 0.f);
    ((float4*)out)[idx] = o;
}

// ---------------- launch ----------------

extern "C" void kernel_launch(void* const* d_in, const int* in_sizes, int n_in,
                              void* d_out, int out_size, void* d_ws, size_t ws_size,
                              hipStream_t stream) {
    const float* x  = (const float*)d_in[0];
    const int*   es = (const int*)d_in[1];
    const float* W1 = (const float*)d_in[2];
    const float* g1 = (const float*)d_in[3];
    const float* b1 = (const float*)d_in[4];
    const float* W2 = (const float*)d_in[5];
    const float* g2 = (const float*)d_in[6];
    const float* b2 = (const float*)d_in[7];
    float* out = (float*)d_out;

    const int E  = in_sizes[1] / 2;
    const int IC = in_sizes[3];   // 512
    const int C  = in_sizes[7];   // 256
    const int N  = in_sizes[0] / C;

    const int* row = es;
    const int* col = es + E;

    // ---- workspace layout ----
    char* w = (char*)d_ws;
    size_t off = 0;
    auto alloc = [&](size_t bytes) -> void* {
        void* p = w + off;
        off = (off + bytes + 255) & ~(size_t)255;
        return p;
    };
    int*   cnt     = (int*)alloc((size_t)N * 4);
    float* dis     = (float*)alloc((size_t)N * 4);
    int*   rowptr  = (int*)alloc((size_t)(N + 1) * 4);
    int*   cursor  = (int*)alloc((size_t)N * 4);
    int*   adj     = (int*)alloc((size_t)E * 4);
    float* bnbuf   = (float*)alloc((size_t)(2 * IC + 2 * C) * 4); // sum1,sumsq1,sum2,sumsq2
    float* sum1    = bnbuf;
    float* sumsq1  = bnbuf + IC;
    float* sum2    = bnbuf + 2 * IC;
    float* sumsq2  = bnbuf + 2 * IC + C;
    float* scale1  = (float*)alloc((size_t)IC * 4);
    float* shift1  = (float*)alloc((size_t)IC * 4);
    float* scale2  = (float*)alloc((size_t)C * 4);
    float* shift2  = (float*)alloc((size_t)C * 4);
    float* h1      = (float*)alloc((size_t)N * IC * 4);
    float* big     = (float*)alloc((size_t)N * IC * 4); // xl1; later xl2 + h2
    float* xl1 = big;
    float* xl2 = big;                      // alias: xl1 dead after gather1
    float* h2  = big + (size_t)N * C;      // distinct from xl2 region

    // ---- zero-init what needs it ----
    hipMemsetAsync(cnt, 0, (size_t)N * 4, stream);
    hipMemsetAsync(bnbuf, 0, (size_t)(2 * IC + 2 * C) * 4, stream);

    // ---- degree + CSR ----
    count_deg_kernel<<<(E + 255) / 256, 256, 0, stream>>>(col, cnt, E);
    dis_kernel<<<(N + 255) / 256, 256, 0, stream>>>(cnt, dis, N);
    scan_kernel<<<1, 1024, 0, stream>>>(cnt, rowptr, cursor, N);
    scatter_kernel<<<(E + 255) / 256, 256, 0, stream>>>(row, col, cursor, adj, E);

    // ---- layer 1 ----
    {
        dim3 grid(IC / 64, (N + 63) / 64);
        gemm_tn_kernel<false><<<grid, 256, 0, stream>>>(x, W1, nullptr, nullptr, xl1, N, IC, C);
    }
    gather_kernel<2><<<N, 256, 0, stream>>>(xl1, rowptr, adj, dis, h1, IC);
    {
        int chunks = 80;
        int rpc = (N + chunks - 1) / chunks;
        bn_stats_kernel<<<chunks, 256, 0, stream>>>(h1, sum1, sumsq1, N, IC, rpc);
    }
    bn_finalize_kernel<<<(IC + 255) / 256, 256, 0, stream>>>(sum1, sumsq1, g1, b1, scale1, shift1, N, IC);

    // ---- layer 2 (BN1+ReLU fused into GEMM2 A-load) ----
    {
        dim3 grid(C / 64, (N + 63) / 64);
        gemm_tn_kernel<true><<<grid, 256, 0, stream>>>(h1, W2, scale1, shift1, xl2, N, C, IC);
    }
    gather_kernel<1><<<N, 256, 0, stream>>>(xl2, rowptr, adj, dis, h2, C);
    {
        int chunks = 80;
        int rpc = (N + chunks - 1) / chunks;
        bn_stats_kernel<<<chunks, 256, 0, stream>>>(h2, sum2, sumsq2, N, C, rpc);
    }
    bn_finalize_kernel<<<(C + 255) / 256, 256, 0, stream>>>(sum2, sumsq2, g2, b2, scale2, shift2, N, C);

    // ---- epilogue: relu(bn2(h2) + x) ----
    {
        int total4 = (N * C) / 4;
        final_kernel<<<(total4 + 255) / 256, 256, 0, stream>>>(h2, x, scale2, shift2, out, total4, C / 4);
    }
}